// Round 10
// baseline (315.794 us; speedup 1.0000x reference)
//
#include <hip/hip_runtime.h>

// ---------------------------------------------------------------------------
// ImprovedLinkingPredictor round 10.
// - r9 MX pipeline + spill fix: GEMM1 2x2 mt-blocking (16 live a-regs, not 32),
//   staging unroll capped at 4 (16 in-flight regs, not 64).
// - attn softmax: no max pass (bounded scores), normalization deferred to the
//   4 PV outputs per row (s_inv in LDS) -> 1 LDS pass instead of 3.
// ---------------------------------------------------------------------------

typedef __attribute__((ext_vector_type(8))) __bf16 bf16x8;    // bf16 MFMA frag
typedef __attribute__((ext_vector_type(4))) float f32x4;      // 16x16 C/D
typedef __attribute__((ext_vector_type(8))) int i32x8;        // 32B fp8 frag

__device__ __forceinline__ float bf2f(unsigned short u) {
    return __uint_as_float(((unsigned int)u) << 16);
}
__device__ __forceinline__ unsigned short f2bf(float f) {
    union { __bf16 b; unsigned short u; } cv;
    cv.b = (__bf16)f;
    return cv.u;
}
__device__ __forceinline__ unsigned pk2(float lo, float hi) {
    return (unsigned)f2bf(lo) | ((unsigned)f2bf(hi) << 16);
}
__device__ __forceinline__ int pk4_fp8(float a, float b, float c, float d) {
    int w = __builtin_amdgcn_cvt_pk_fp8_f32(a, b, 0, false);
    w = __builtin_amdgcn_cvt_pk_fp8_f32(c, d, w, true);
    return w;
}
__device__ __forceinline__ unsigned char f2fp8(float v) {
    return (unsigned char)(__builtin_amdgcn_cvt_pk_fp8_f32(v, 0.f, 0, false) & 0xff);
}
__device__ __forceinline__ bf16x8 load8f_bf(const float* p) {
    float4 a = *reinterpret_cast<const float4*>(p);
    float4 b = *reinterpret_cast<const float4*>(p + 4);
    union { bf16x8 v; unsigned u[4]; } cv;
    cv.u[0] = pk2(a.x, a.y); cv.u[1] = pk2(a.z, a.w);
    cv.u[2] = pk2(b.x, b.y); cv.u[3] = pk2(b.z, b.w);
    return cv.v;
}
__device__ __forceinline__ i32x8 ld32_lds(const unsigned char* p) {
    union { i32x8 v; uint4 q[2]; } r;
    r.q[0] = *reinterpret_cast<const uint4*>(p);
    r.q[1] = *reinterpret_cast<const uint4*>(p + 16);
    return r.v;
}
#define SC1 0x7F7F7F7F   // e8m0 scale = 1.0 in all bytes
#define MFMA_MX(a, b, c) __builtin_amdgcn_mfma_scale_f32_16x16x128_f8f6f4( \
        (a), (b), (c), 0, 0, 0, SC1, 0, SC1)

// ---------------- pack_all: packing + Wcomb + qkv GEMM ---------------------
__global__ __launch_bounds__(256) void pack_all(
    const float* __restrict__ features, const float* __restrict__ in_proj_w,
    const float* __restrict__ in_proj_b, const float* __restrict__ out_proj_w,
    const float* __restrict__ w1, const float* __restrict__ w2,
    const float* __restrict__ w3, const float* __restrict__ w4,
    const float* __restrict__ b1, const float* __restrict__ ln_g,
    const float* __restrict__ ln_b, const float* __restrict__ b2,
    const float* __restrict__ out_proj_b,
    unsigned short* __restrict__ qkvb, unsigned short* __restrict__ Vt,
    unsigned short* __restrict__ WcatB,
    unsigned char* __restrict__ w1c_mx, unsigned char* __restrict__ w1t_f8,
    unsigned char* __restrict__ w2g_mx, unsigned char* __restrict__ w3_mx,
    unsigned char* __restrict__ w4_f8,
    float* __restrict__ bias768, float* __restrict__ c1, float* __restrict__ c2)
{
    const int blk = blockIdx.x;
    if (blk < 716) {
        int t = blk * 256 + threadIdx.x;
        if (t < 65536) {                                // WcatB rows 0..255 = outW
            WcatB[t] = f2bf(out_proj_w[t]);
        } else if (t < 131072) {                        // w1c_mx: K=256 N=256, MX frag
            int u = t - 65536;
            int e = u & 31, lane = (u >> 5) & 63, f = u >> 11;
            int mt = f & 15, ks = f >> 4;
            int o = mt * 16 + (lane & 15);
            int k = ks * 128 + ((lane >> 4) & 3) * 32 + e;
            w1c_mx[u] = f2fp8(w1[o * 771 + 512 + k]);
        } else if (t < 139264) {                        // w1t_f8: spatial tail
            int u = t - 131072;
            int e = u & 7, lane = (u >> 3) & 63, f = u >> 9;
            int o = f * 16 + (lane & 15);
            int k = ((lane >> 4) & 3) * 8 + e;
            float v = (k < 3) ? w1[o * 771 + 768 + k] : 0.f;
            w1t_f8[u] = f2fp8(v);
        } else if (t < 172032) {                        // w2g_mx = w2*ln_g
            int u = t - 139264;
            int e = u & 31, lane = (u >> 5) & 63, f = u >> 11;
            int mt = f & 7, ks = f >> 3;
            int p = mt * 16 + (lane & 15);
            int k = ks * 128 + ((lane >> 4) & 3) * 32 + e;
            w2g_mx[u] = f2fp8(w2[p * 256 + k] * ln_g[k]);
        } else if (t < 180224) {                        // w3_mx: K=128 N=64
            int u = t - 172032;
            int e = u & 31, lane = (u >> 5) & 63, f = u >> 11;
            int o = f * 16 + (lane & 15);
            int k = ((lane >> 4) & 3) * 32 + e;
            w3_mx[u] = f2fp8(w3[o * 128 + k]);
        } else if (t < 182272) {                        // w4_f8 K=64 N=32 (16x16x32)
            int u = t - 180224;
            int e = u & 7, lane = (u >> 3) & 63, f = u >> 9;
            int l15 = lane & 15, quad = lane >> 4;
            int ct = f & 1, kc = f >> 1;
            int o = ct * 16 + l15, k = kc * 32 + quad * 8 + e;
            w4_f8[u] = f2fp8(w4[o * 64 + k]);
        } else if (t < 183040) {                        // bias768
            int n = t - 182272;
            if (n < 256) bias768[n] = out_proj_b[n];
            else {
                int m = n - 256;
                float s = 0.f;
                for (int d = 0; d < 256; d += 4) {
                    float4 ob = *reinterpret_cast<const float4*>(&out_proj_b[d]);
                    const float* wr = (m < 256) ? &w1[m * 771 + d]
                                                : &w1[(m - 256) * 771 + 256 + d];
                    float4 w = *reinterpret_cast<const float4*>(wr);
                    s += ob.x * w.x + ob.y * w.y + ob.z * w.z + ob.w * w.w;
                }
                bias768[n] = s + ((m < 256) ? b1[m] : 0.f);
            }
        } else if (t < 183168) {                        // c1/c2 LN-fold constants
            int p = t - 183040;
            float s2 = 0.f, s1 = 0.f;
            for (int k = 0; k < 256; k += 4) {
                float4 w = *reinterpret_cast<const float4*>(&w2[p * 256 + k]);
                float4 g = *reinterpret_cast<const float4*>(&ln_g[k]);
                float4 lb = *reinterpret_cast<const float4*>(&ln_b[k]);
                s2 += g.x * w.x + g.y * w.y + g.z * w.z + g.w * w.w;
                s1 += lb.x * w.x + lb.y * w.y + lb.z * w.z + lb.w * w.w;
            }
            c2[p] = s2;
            c1[p] = s1 + b2[p];
        }
    } else if (blk < 1228) {
        // ---- Wcomb[n][e] = sum_d wAB[n][d] * outW[d][e] -> WcatB rows 256+n
        const int n = blk - 716, e = threadIdx.x;
        const float* wrow = (n < 256) ? &w1[n * 771] : &w1[(n - 256) * 771 + 256];
        float acc = 0.f;
        for (int d = 0; d < 256; d += 4) {
            float4 w = *reinterpret_cast<const float4*>(&wrow[d]);
            acc += w.x * out_proj_w[(d + 0) * 256 + e];
            acc += w.y * out_proj_w[(d + 1) * 256 + e];
            acc += w.z * out_proj_w[(d + 2) * 256 + e];
            acc += w.w * out_proj_w[(d + 3) * 256 + e];
        }
        WcatB[(256 + n) * 256 + e] = f2bf(acc);
    } else {
        // ---- qkv GEMM (raw fp32 inputs, inline cvt): 144 blocks, 64x64 ----
        const int q = blk - 1228;
        const int bm = q % 12, bn = q / 12;
        const int wv = threadIdx.x >> 6, lane = threadIdx.x & 63;
        const int l15 = lane & 15, quad = lane >> 4;
        const int row0 = bm * 64 + wv * 16;
        const int col0 = bn * 64;
        f32x4 acc[4] = {};
        for (int kc = 0; kc < 8; ++kc) {
            bf16x8 a = load8f_bf(&features[(row0 + l15) * 256 + kc * 32 + quad * 8]);
#pragma unroll
            for (int ct = 0; ct < 4; ++ct) {
                bf16x8 b = load8f_bf(&in_proj_w[(col0 + ct * 16 + l15) * 256 + kc * 32 + quad * 8]);
                acc[ct] = __builtin_amdgcn_mfma_f32_16x16x32_bf16(a, b, acc[ct], 0, 0, 0);
            }
        }
#pragma unroll
        for (int ct = 0; ct < 4; ++ct)
#pragma unroll
            for (int r = 0; r < 4; ++r) {
                int row = row0 + quad * 4 + r, col = col0 + ct * 16 + l15;
                float v = acc[ct][r] + in_proj_b[col];
                if (col < 512) qkvb[row * 768 + col] = f2bf(v);
                else           Vt[(col - 512) * 768 + row] = f2bf(v);
            }
    }
}

// ---------------- fused [att | AB] GEMM ------------------------------------
__global__ __launch_bounds__(256) void gemm_attab(
    const unsigned short* __restrict__ A, const unsigned short* __restrict__ W,
    const float* __restrict__ bias, float* __restrict__ att,
    float* __restrict__ AB)
{
    const int wv = threadIdx.x >> 6, lane = threadIdx.x & 63;
    const int l15 = lane & 15, quad = lane >> 4;
    const int row0 = blockIdx.x * 64 + wv * 16;
    const int col0 = blockIdx.y * 64;
    f32x4 acc[4] = {};
    for (int kc = 0; kc < 8; ++kc) {
        bf16x8 a = *reinterpret_cast<const bf16x8*>(&A[(row0 + l15) * 256 + kc * 32 + quad * 8]);
#pragma unroll
        for (int ct = 0; ct < 4; ++ct) {
            bf16x8 b = *reinterpret_cast<const bf16x8*>(&W[(col0 + ct * 16 + l15) * 256 + kc * 32 + quad * 8]);
            acc[ct] = __builtin_amdgcn_mfma_f32_16x16x32_bf16(a, b, acc[ct], 0, 0, 0);
        }
    }
#pragma unroll
    for (int ct = 0; ct < 4; ++ct)
#pragma unroll
        for (int r = 0; r < 4; ++r) {
            int row = row0 + quad * 4 + r, col = col0 + ct * 16 + l15;
            float v = acc[ct][r] + bias[col];
            if (col < 256) att[row * 256 + col] = v;
            else           AB[row * 512 + (col - 256)] = v;
        }
}

// ---------------- fused MFMA attention: 32-row q-tiles, 1-pass softmax -----
#define SP 776

__global__ __launch_bounds__(256) void attn_mfma(
    const unsigned short* __restrict__ qkvb, const unsigned short* __restrict__ Vt,
    unsigned short* __restrict__ Obf)
{
    __shared__ __align__(16) unsigned short smS[32 * SP];   // 49.7 KB
    __shared__ float s_inv[32];
    const int h = blockIdx.x, q0 = blockIdx.y * 32, hb = h * 32;
    const int tid = threadIdx.x, wave = tid >> 6, lane = tid & 63;
    const int l15 = lane & 15, quad = lane >> 4;

    bf16x8 af[2];
#pragma unroll
    for (int mt = 0; mt < 2; ++mt)
        af[mt] = *reinterpret_cast<const bf16x8*>(&qkvb[(q0 + mt * 16 + l15) * 768 + hb + quad * 8]);
#pragma unroll
    for (int ct = 0; ct < 12; ++ct) {
        int n0 = wave * 192 + ct * 16;
        bf16x8 b = *reinterpret_cast<const bf16x8*>(&qkvb[(n0 + l15) * 768 + 256 + hb + quad * 8]);
#pragma unroll
        for (int mt = 0; mt < 2; ++mt) {
            f32x4 c = {};
            c = __builtin_amdgcn_mfma_f32_16x16x32_bf16(af[mt], b, c, 0, 0, 0);
#pragma unroll
            for (int r = 0; r < 4; ++r)
                smS[(mt * 16 + quad * 4 + r) * SP + n0 + l15] =
                    f2bf(c[r] * 0.17677669529663689f);
        }
    }
    __syncthreads();

    {   // 1-pass softmax: exp (unnormalized, scores bounded) + row sum
        const int row = tid >> 3, part = tid & 7;
        unsigned short* rp = &smS[row * SP + part * 96];
        float ls = 0.f;
#pragma unroll
        for (int c8 = 0; c8 < 12; ++c8) {
            uint4 v = *reinterpret_cast<const uint4*>(&rp[c8 * 8]);
            const unsigned short* pe = reinterpret_cast<const unsigned short*>(&v);
            unsigned short o8[8];
#pragma unroll
            for (int e = 0; e < 8; ++e) {
                float ev = __expf(bf2f(pe[e]));
                ls += ev;
                o8[e] = f2bf(ev);
            }
            *reinterpret_cast<uint4*>(&rp[c8 * 8]) = *reinterpret_cast<const uint4*>(o8);
        }
        ls += __shfl_xor(ls, 1, 64);
        ls += __shfl_xor(ls, 2, 64);
        ls += __shfl_xor(ls, 4, 64);
        if (part == 0) s_inv[row] = 1.0f / ls;
    }
    __syncthreads();

    // PV on unnormalized P; normalize the 4 outputs per row at the end.
    const int row0 = (wave >> 1) * 16, cg = wave & 1;
    f32x4 accp = {};
    for (int kc = 0; kc < 24; ++kc) {
        bf16x8 a = *reinterpret_cast<const bf16x8*>(&smS[(row0 + l15) * SP + kc * 32 + quad * 8]);
        bf16x8 b = *reinterpret_cast<const bf16x8*>(&Vt[(hb + cg * 16 + l15) * 768 + kc * 32 + quad * 8]);
        accp = __builtin_amdgcn_mfma_f32_16x16x32_bf16(a, b, accp, 0, 0, 0);
    }
#pragma unroll
    for (int r = 0; r < 4; ++r) {
        int rloc = row0 + quad * 4 + r;
        Obf[(q0 + rloc) * 256 + hb + cg * 16 + l15] = f2bf(accp[r] * s_inv[rloc]);
    }
}

// ---------------- fused pair MLP (MX fp8), 1 i x 64 j ----------------------
#define S1 304   // scaledA/h1 row stride: 288 data + 16 pad
#define S2 144   // h2 row stride: 128 data + 16 pad
#define S3 72    // h3 row stride: 64 data + 8 pad

__global__ __launch_bounds__(256, 4) void pair_mlp(
    const float* __restrict__ att, const float* __restrict__ AB,
    const unsigned char* __restrict__ w1c_mx, const unsigned char* __restrict__ w1t_f8,
    const unsigned char* __restrict__ w2g_mx, const unsigned char* __restrict__ w3_mx,
    const unsigned char* __restrict__ w4_f8,
    const float* __restrict__ boxes,
    const float* __restrict__ c1, const float* __restrict__ c2,
    const float* __restrict__ b3, const float* __restrict__ b4,
    const float* __restrict__ w5, const float* __restrict__ b5,
    float* __restrict__ out)
{
    __shared__ __align__(16) unsigned char smH[64 * S1];    // scaledA -> h1
    __shared__ __align__(16) unsigned char smH2[64 * S2];   // h2
    __shared__ __align__(16) unsigned char smH3[64 * S3];   // h3
    __shared__ float s_psum[64][4], s_pssq[64][4];
    __shared__ float s_mu[64], s_rs[64];
    __shared__ float s_l5[64][2];

    const int i    = blockIdx.x;
    const int j0   = blockIdx.y * 64;
    const int tid  = threadIdx.x;
    const int wave = tid >> 6;
    const int lane = tid & 63;
    const int l15  = lane & 15;
    const int quad = lane >> 4;

    // ---- stage scaledA fp8 from f32 att (unroll capped: 4 loads in flight) --
    {
        const int g = tid & 63;
        float4 fi4 = *reinterpret_cast<const float4*>(&att[i * 256 + g * 4]);
#pragma unroll 4
        for (int it = 0; it < 16; ++it) {
            int r = (tid >> 6) + it * 4;
            float4 aj = *reinterpret_cast<const float4*>(&att[(j0 + r) * 256 + g * 4]);
            *reinterpret_cast<int*>(&smH[r * S1 + g * 4]) =
                pk4_fp8(aj.x * fi4.x, aj.y * fi4.y, aj.z * fi4.z, aj.w * fi4.w);
        }
    }
    if (tid < 64) {   // spatial tail cols 256..287
        int j = j0 + tid;
        float xd = fabsf(boxes[i * 4 + 0] - boxes[j * 4 + 0]);
        float yd = boxes[i * 4 + 1] - boxes[j * 4 + 1];
        *reinterpret_cast<int*>(&smH[tid * S1 + 256]) = pk4_fp8(xd, fabsf(yd), yd, 0.f);
        *reinterpret_cast<int*>(&smH[tid * S1 + 260]) = 0;
        *reinterpret_cast<long long*>(&smH[tid * S1 + 264]) = 0;
        *reinterpret_cast<long long*>(&smH[tid * S1 + 272]) = 0;
        *reinterpret_cast<long long*>(&smH[tid * S1 + 280]) = 0;
    }
    __syncthreads();                                          // B0

    // ======== GEMM1: 2x MX(K=128) + 16x16x32 tail; 2x2 mt-blocking ========
    f32x4 acc1[4][4] = {};   // [mt (o)][nt (j)]
#pragma unroll
    for (int ks = 0; ks < 2; ++ks) {
#pragma unroll
        for (int mh = 0; mh < 2; ++mh) {
            i32x8 a0 = *reinterpret_cast<const i32x8*>(&w1c_mx[((ks * 16 + wave * 4 + mh * 2 + 0) * 64 + lane) * 32]);
            i32x8 a1 = *reinterpret_cast<const i32x8*>(&w1c_mx[((ks * 16 + wave * 4 + mh * 2 + 1) * 64 + lane) * 32]);
#pragma unroll
            for (int nt = 0; nt < 4; ++nt) {
                i32x8 b = ld32_lds(&smH[(nt * 16 + l15) * S1 + ks * 128 + quad * 32]);
                acc1[mh * 2 + 0][nt] = MFMA_MX(a0, b, acc1[mh * 2 + 0][nt]);
                acc1[mh * 2 + 1][nt] = MFMA_MX(a1, b, acc1[mh * 2 + 1][nt]);
            }
        }
    }
    {   // spatial tail k = 256..287 (2x2 blocking, small regs anyway)
#pragma unroll
        for (int mh = 0; mh < 2; ++mh) {
            long long a0 = *reinterpret_cast<const long long*>(&w1t_f8[((wave * 4 + mh * 2 + 0) * 64 + lane) * 8]);
            long long a1 = *reinterpret_cast<const long long*>(&w1t_f8[((wave * 4 + mh * 2 + 1) * 64 + lane) * 8]);
#pragma unroll
            for (int nt = 0; nt < 4; ++nt) {
                long long b = *reinterpret_cast<const long long*>(&smH[(nt * 16 + l15) * S1 + 256 + quad * 8]);
                acc1[mh * 2 + 0][nt] = __builtin_amdgcn_mfma_f32_16x16x32_fp8_fp8(a0, b, acc1[mh * 2 + 0][nt], 0, 0, 0);
                acc1[mh * 2 + 1][nt] = __builtin_amdgcn_mfma_f32_16x16x32_fp8_fp8(a1, b, acc1[mh * 2 + 1][nt], 0, 0, 0);
            }
        }
    }

    // ---- epilogue1: + A_i[o] + B_j[o], relu, stats ----
    const int o0 = wave * 64;
    float vsum[4] = {}, vssq[4] = {};
#pragma unroll
    for (int mt = 0; mt < 4; ++mt) {
        int o = o0 + mt * 16 + quad * 4;
        float4 Ai = *reinterpret_cast<const float4*>(&AB[i * 512 + o]);
        float AiA[4] = {Ai.x, Ai.y, Ai.z, Ai.w};
#pragma unroll
        for (int nt = 0; nt < 4; ++nt) {
            int j = nt * 16 + l15;
            float4 Bj = *reinterpret_cast<const float4*>(&AB[(j0 + j) * 512 + 256 + o]);
            float BjA[4] = {Bj.x, Bj.y, Bj.z, Bj.w};
#pragma unroll
            for (int r = 0; r < 4; ++r) {
                float v = fmaxf(acc1[mt][nt][r] + AiA[r] + BjA[r], 0.f);
                acc1[mt][nt][r] = v;
                vsum[nt] += v; vssq[nt] += v * v;
            }
        }
    }
#pragma unroll
    for (int nt = 0; nt < 4; ++nt) {
        vsum[nt] += __shfl_xor(vsum[nt], 16, 64);
        vsum[nt] += __shfl_xor(vsum[nt], 32, 64);
        vssq[nt] += __shfl_xor(vssq[nt], 16, 64);
        vssq[nt] += __shfl_xor(vssq[nt], 32, 64);
    }
    if (quad == 0)
#pragma unroll
        for (int nt = 0; nt < 4; ++nt) {
            s_psum[nt * 16 + l15][wave] = vsum[nt];
            s_pssq[nt * 16 + l15][wave] = vssq[nt];
        }
    __syncthreads();                                          // B1: GEMM1 reads done
    // h1 fp8 write into smH (overwrites scaledA; WAR cleared by B1)
#pragma unroll
    for (int mt = 0; mt < 4; ++mt) {
        int o = o0 + mt * 16 + quad * 4;
#pragma unroll
        for (int nt = 0; nt < 4; ++nt) {
            int j = nt * 16 + l15;
            *reinterpret_cast<int*>(&smH[j * S1 + o]) =
                pk4_fp8(acc1[mt][nt][0], acc1[mt][nt][1], acc1[mt][nt][2], acc1[mt][nt][3]);
        }
    }
    if (wave == 0) {   // finalize LN stats
        int j = lane;
        float sm = (s_psum[j][0] + s_psum[j][1] + s_psum[j][2] + s_psum[j][3]) * (1.0f / 256.0f);
        float sq = (s_pssq[j][0] + s_pssq[j][1] + s_pssq[j][2] + s_pssq[j][3]) * (1.0f / 256.0f);
        s_mu[j] = sm;
        s_rs[j] = rsqrtf(sq - sm * sm + 1e-5f);
    }
    __syncthreads();                                          // B2: h1 + stats ready

    // ======== GEMM2 (MX, K=256): wave owns p-slice 32 ========
    f32x4 acc2[2][4] = {};
#pragma unroll
    for (int ks = 0; ks < 2; ++ks) {
        i32x8 a0 = *reinterpret_cast<const i32x8*>(&w2g_mx[((ks * 8 + wave * 2 + 0) * 64 + lane) * 32]);
        i32x8 a1 = *reinterpret_cast<const i32x8*>(&w2g_mx[((ks * 8 + wave * 2 + 1) * 64 + lane) * 32]);
#pragma unroll
        for (int nt = 0; nt < 4; ++nt) {
            i32x8 b = ld32_lds(&smH[(nt * 16 + l15) * S1 + ks * 128 + quad * 32]);
            acc2[0][nt] = MFMA_MX(a0, b, acc2[0][nt]);
            acc2[1][nt] = MFMA_MX(a1, b, acc2[1][nt]);
        }
    }
    // epilogue2: LN-folded affine + relu -> h2 (separate region, no barrier)
#pragma unroll
    for (int mt = 0; mt < 2; ++mt) {
        int p = wave * 32 + mt * 16 + quad * 4;
        float4 C1 = *reinterpret_cast<const float4*>(&c1[p]);
        float4 C2 = *reinterpret_cast<const float4*>(&c2[p]);
        float C1A[4] = {C1.x, C1.y, C1.z, C1.w};
        float C2A[4] = {C2.x, C2.y, C2.z, C2.w};
#pragma unroll
        for (int nt = 0; nt < 4; ++nt) {
            int j = nt * 16 + l15;
            float mu = s_mu[j], rs = s_rs[j];
            float vv[4];
#pragma unroll
            for (int r = 0; r < 4; ++r)
                vv[r] = fmaxf(rs * (acc2[mt][nt][r] - mu * C2A[r]) + C1A[r], 0.f);
            *reinterpret_cast<int*>(&smH2[j * S2 + p]) = pk4_fp8(vv[0], vv[1], vv[2], vv[3]);
        }
    }
    __syncthreads();                                          // B3: h2 ready

    // ======== GEMM3 (MX, K=128): wave owns q-slice 16 ========
    f32x4 acc3[4] = {};
    {
        i32x8 a = *reinterpret_cast<const i32x8*>(&w3_mx[(wave * 64 + lane) * 32]);
#pragma unroll
        for (int nt = 0; nt < 4; ++nt) {
            i32x8 b = ld32_lds(&smH2[(nt * 16 + l15) * S2 + quad * 32]);
            acc3[nt] = MFMA_MX(a, b, acc3[nt]);
        }
    }
    {   // epilogue3 -> h3 (separate region, no pre-barrier)
        int q = wave * 16 + quad * 4;
        float4 B3 = *reinterpret_cast<const float4*>(&b3[q]);
        float B3A[4] = {B3.x, B3.y, B3.z, B3.w};
#pragma unroll
        for (int nt = 0; nt < 4; ++nt) {
            int j = nt * 16 + l15;
            float vv[4];
#pragma unroll
            for (int r = 0; r < 4; ++r)
                vv[r] = fmaxf(acc3[nt][r] + B3A[r], 0.f);
            *reinterpret_cast<int*>(&smH3[j * S3 + q]) = pk4_fp8(vv[0], vv[1], vv[2], vv[3]);
        }
    }
    __syncthreads();                                          // B4: h3 ready

    // ======== GEMM4 (16x16x32 fp8, K=64) + head ========
    const int mt4 = wave & 1;
    const int jh  = wave >> 1;
    f32x4 acc4[2] = {};
#pragma unroll
    for (int kc = 0; kc < 2; ++kc) {
        long long a = *reinterpret_cast<const long long*>(&w4_f8[((kc * 2 + mt4) * 64 + lane) * 8]);
#pragma unroll
        for (int nt = 0; nt < 2; ++nt) {
            int j = jh * 32 + nt * 16 + l15;
            long long b = *reinterpret_cast<const long long*>(&smH3[j * S3 + kc * 32 + quad * 8]);
            acc4[nt] = __builtin_amdgcn_mfma_f32_16x16x32_fp8_fp8(a, b, acc4[nt], 0, 0, 0);
        }
    }
    {
        int o4 = mt4 * 16 + quad * 4;
        float4 B4 = *reinterpret_cast<const float4*>(&b4[o4]);
        float4 W5 = *reinterpret_cast<const float4*>(&w5[o4]);
        float B4A[4] = {B4.x, B4.y, B4.z, B4.w};
        float W5A[4] = {W5.x, W5.y, W5.z, W5.w};
#pragma unroll
        for (int nt = 0; nt < 2; ++nt) {
            float part = 0.f;
#pragma unroll
            for (int r = 0; r < 4; ++r)
                part += fmaxf(acc4[nt][r] + B4A[r], 0.f) * W5A[r];
            part += __shfl_xor(part, 16, 64);
            part += __shfl_xor(part, 32, 64);
            if (quad == 0)
                s_l5[jh * 32 + nt * 16 + l15][mt4] = part;
        }
    }
    __syncthreads();                                          // B5
    if (tid < 64) {
        int j = j0 + tid;
        float v = s_l5[tid][0] + s_l5[tid][1] + b5[0];
        out[i * 768 + j] = (j == i) ? -1.0e9f : v;
    }
}

// ---------------------------------------------------------------------------
extern "C" void kernel_launch(void* const* d_in, const int* in_sizes, int n_in,
                              void* d_out, int out_size, void* d_ws, size_t ws_size,
                              hipStream_t stream)
{
    const float* features   = (const float*)d_in[0];
    const float* boxes      = (const float*)d_in[1];
    const float* in_proj_w  = (const float*)d_in[2];
    const float* in_proj_b  = (const float*)d_in[3];
    const float* out_proj_w = (const float*)d_in[4];
    const float* out_proj_b = (const float*)d_in[5];
    const float* w1  = (const float*)d_in[6];
    const float* b1  = (const float*)d_in[7];
    const float* ln_g = (const float*)d_in[8];
    const float* ln_b = (const float*)d_in[9];
    const float* w2  = (const float*)d_in[10];
    const float* b2  = (const float*)d_in[11];
    const float* w3  = (const float*)d_in[12];
    const float* b3  = (const float*)d_in[13];
    const float* w4  = (const float*)d_in[14];
    const float* b4  = (const float*)d_in[15];
    const float* w5  = (const float*)d_in[16];
    const float* b5  = (const float*)d_in[17];
    float* out = (float*)d_out;

    // ---- workspace layout ----
    char* p = (char*)d_ws;
    unsigned short* qkvb  = (unsigned short*)p; p += 768 * 768 * 2;
    unsigned short* Vt    = (unsigned short*)p; p += 256 * 768 * 2;
    unsigned short* Obf   = (unsigned short*)p; p += 768 * 256 * 2;
    unsigned short* WcatB = (unsigned short*)p; p += 196608 * 2;   // [outW;Wcomb]
    float* att = (float*)p; p += 768 * 256 * 4;
    float* AB  = (float*)p; p += 768 * 512 * 4;
    unsigned char* w1c_mx = (unsigned char*)p; p += 65536;
    unsigned char* w1t_f8 = (unsigned char*)p; p += 8192;
    unsigned char* w2g_mx = (unsigned char*)p; p += 32768;
    unsigned char* w3_mx  = (unsigned char*)p; p += 8192;
    unsigned char* w4_f8  = (unsigned char*)p; p += 2048;
    float* bias768 = (float*)p; p += 768 * 4;
    float* c1v     = (float*)p; p += 128 * 4;
    float* c2v     = (float*)p; p += 128 * 4;

    // 1) pack + Wcomb + qkv GEMM
    pack_all<<<dim3(1372), dim3(256), 0, stream>>>(features, in_proj_w,
        in_proj_b, out_proj_w, w1, w2, w3, w4, b1, ln_g, ln_b, b2, out_proj_b,
        qkvb, Vt, WcatB, w1c_mx, w1t_f8, w2g_mx, w3_mx, w4_f8,
        bias768, c1v, c2v);
    // 2) attention
    attn_mfma<<<dim3(8, 24), dim3(256), 0, stream>>>(qkvb, Vt, Obf);
    // 3) [att | AB] = O @ WcatB^T + bias768
    gemm_attab<<<dim3(12, 12), dim3(256), 0, stream>>>(Obf, WcatB, bias768,
        att, AB);
    // 4) pair MLP
    pair_mlp<<<dim3(768, 12), dim3(256), 0, stream>>>(att, AB,
        w1c_mx, w1t_f8, w2g_mx, w3_mx, w4_f8, boxes, c1v, c2v,
        b3, b4, w5, b5, out);
}

// Round 11
// 296.986 us; speedup vs baseline: 1.0633x; 1.0633x over previous
//
#include <hip/hip_runtime.h>

// ---------------------------------------------------------------------------
// ImprovedLinkingPredictor round 11.
// - pair_mlp: 512 thr / 8 waves per 64-j tile. Wave slices: GEMM1 o=32,
//   GEMM2 p=16, GEMM3 (q-tile, j-half), GEMM4 (o-tile, j-quarter).
//   Halves per-wave acc+operand registers vs r9/r10 -> no scratch spill,
//   same per-CU work (2 blocks x 8 waves = 16 waves/CU).
// - MX fp8 GEMM1/2/3 (scale=1.0), fp8 16x16x32 tail + GEMM4.
// - r10 1-pass attention kept.
// ---------------------------------------------------------------------------

typedef __attribute__((ext_vector_type(8))) __bf16 bf16x8;    // bf16 MFMA frag
typedef __attribute__((ext_vector_type(4))) float f32x4;      // 16x16 C/D
typedef __attribute__((ext_vector_type(8))) int i32x8;        // 32B fp8 frag

__device__ __forceinline__ float bf2f(unsigned short u) {
    return __uint_as_float(((unsigned int)u) << 16);
}
__device__ __forceinline__ unsigned short f2bf(float f) {
    union { __bf16 b; unsigned short u; } cv;
    cv.b = (__bf16)f;
    return cv.u;
}
__device__ __forceinline__ unsigned pk2(float lo, float hi) {
    return (unsigned)f2bf(lo) | ((unsigned)f2bf(hi) << 16);
}
__device__ __forceinline__ int pk4_fp8(float a, float b, float c, float d) {
    int w = __builtin_amdgcn_cvt_pk_fp8_f32(a, b, 0, false);
    w = __builtin_amdgcn_cvt_pk_fp8_f32(c, d, w, true);
    return w;
}
__device__ __forceinline__ unsigned char f2fp8(float v) {
    return (unsigned char)(__builtin_amdgcn_cvt_pk_fp8_f32(v, 0.f, 0, false) & 0xff);
}
__device__ __forceinline__ bf16x8 load8f_bf(const float* p) {
    float4 a = *reinterpret_cast<const float4*>(p);
    float4 b = *reinterpret_cast<const float4*>(p + 4);
    union { bf16x8 v; unsigned u[4]; } cv;
    cv.u[0] = pk2(a.x, a.y); cv.u[1] = pk2(a.z, a.w);
    cv.u[2] = pk2(b.x, b.y); cv.u[3] = pk2(b.z, b.w);
    return cv.v;
}
__device__ __forceinline__ i32x8 ld32_lds(const unsigned char* p) {
    union { i32x8 v; uint4 q[2]; } r;
    r.q[0] = *reinterpret_cast<const uint4*>(p);
    r.q[1] = *reinterpret_cast<const uint4*>(p + 16);
    return r.v;
}
#define SC1 0x7F7F7F7F   // e8m0 scale = 1.0 in all bytes
#define MFMA_MX(a, b, c) __builtin_amdgcn_mfma_scale_f32_16x16x128_f8f6f4( \
        (a), (b), (c), 0, 0, 0, SC1, 0, SC1)

// ---------------- pack_all: packing + Wcomb + qkv GEMM ---------------------
__global__ __launch_bounds__(256) void pack_all(
    const float* __restrict__ features, const float* __restrict__ in_proj_w,
    const float* __restrict__ in_proj_b, const float* __restrict__ out_proj_w,
    const float* __restrict__ w1, const float* __restrict__ w2,
    const float* __restrict__ w3, const float* __restrict__ w4,
    const float* __restrict__ b1, const float* __restrict__ ln_g,
    const float* __restrict__ ln_b, const float* __restrict__ b2,
    const float* __restrict__ out_proj_b,
    unsigned short* __restrict__ qkvb, unsigned short* __restrict__ Vt,
    unsigned short* __restrict__ WcatB,
    unsigned char* __restrict__ w1c_mx, unsigned char* __restrict__ w1t_f8,
    unsigned char* __restrict__ w2g_mx, unsigned char* __restrict__ w3_mx,
    unsigned char* __restrict__ w4_f8,
    float* __restrict__ bias768, float* __restrict__ c1, float* __restrict__ c2)
{
    const int blk = blockIdx.x;
    if (blk < 716) {
        int t = blk * 256 + threadIdx.x;
        if (t < 65536) {                                // WcatB rows 0..255 = outW
            WcatB[t] = f2bf(out_proj_w[t]);
        } else if (t < 131072) {                        // w1c_mx: K=256 N=256, MX frag
            int u = t - 65536;
            int e = u & 31, lane = (u >> 5) & 63, f = u >> 11;
            int mt = f & 15, ks = f >> 4;
            int o = mt * 16 + (lane & 15);
            int k = ks * 128 + ((lane >> 4) & 3) * 32 + e;
            w1c_mx[u] = f2fp8(w1[o * 771 + 512 + k]);
        } else if (t < 139264) {                        // w1t_f8: spatial tail
            int u = t - 131072;
            int e = u & 7, lane = (u >> 3) & 63, f = u >> 9;
            int o = f * 16 + (lane & 15);
            int k = ((lane >> 4) & 3) * 8 + e;
            float v = (k < 3) ? w1[o * 771 + 768 + k] : 0.f;
            w1t_f8[u] = f2fp8(v);
        } else if (t < 172032) {                        // w2g_mx = w2*ln_g
            int u = t - 139264;
            int e = u & 31, lane = (u >> 5) & 63, f = u >> 11;
            int mt = f & 7, ks = f >> 3;
            int p = mt * 16 + (lane & 15);
            int k = ks * 128 + ((lane >> 4) & 3) * 32 + e;
            w2g_mx[u] = f2fp8(w2[p * 256 + k] * ln_g[k]);
        } else if (t < 180224) {                        // w3_mx: K=128 N=64
            int u = t - 172032;
            int e = u & 31, lane = (u >> 5) & 63, f = u >> 11;
            int o = f * 16 + (lane & 15);
            int k = ((lane >> 4) & 3) * 32 + e;
            w3_mx[u] = f2fp8(w3[o * 128 + k]);
        } else if (t < 182272) {                        // w4_f8 K=64 N=32 (16x16x32)
            int u = t - 180224;
            int e = u & 7, lane = (u >> 3) & 63, f = u >> 9;
            int l15 = lane & 15, quad = lane >> 4;
            int ct = f & 1, kc = f >> 1;
            int o = ct * 16 + l15, k = kc * 32 + quad * 8 + e;
            w4_f8[u] = f2fp8(w4[o * 64 + k]);
        } else if (t < 183040) {                        // bias768
            int n = t - 182272;
            if (n < 256) bias768[n] = out_proj_b[n];
            else {
                int m = n - 256;
                float s = 0.f;
                for (int d = 0; d < 256; d += 4) {
                    float4 ob = *reinterpret_cast<const float4*>(&out_proj_b[d]);
                    const float* wr = (m < 256) ? &w1[m * 771 + d]
                                                : &w1[(m - 256) * 771 + 256 + d];
                    float4 w = *reinterpret_cast<const float4*>(wr);
                    s += ob.x * w.x + ob.y * w.y + ob.z * w.z + ob.w * w.w;
                }
                bias768[n] = s + ((m < 256) ? b1[m] : 0.f);
            }
        } else if (t < 183168) {                        // c1/c2 LN-fold constants
            int p = t - 183040;
            float s2 = 0.f, s1 = 0.f;
            for (int k = 0; k < 256; k += 4) {
                float4 w = *reinterpret_cast<const float4*>(&w2[p * 256 + k]);
                float4 g = *reinterpret_cast<const float4*>(&ln_g[k]);
                float4 lb = *reinterpret_cast<const float4*>(&ln_b[k]);
                s2 += g.x * w.x + g.y * w.y + g.z * w.z + g.w * w.w;
                s1 += lb.x * w.x + lb.y * w.y + lb.z * w.z + lb.w * w.w;
            }
            c2[p] = s2;
            c1[p] = s1 + b2[p];
        }
    } else if (blk < 1228) {
        // ---- Wcomb[n][e] = sum_d wAB[n][d] * outW[d][e] -> WcatB rows 256+n
        const int n = blk - 716, e = threadIdx.x;
        const float* wrow = (n < 256) ? &w1[n * 771] : &w1[(n - 256) * 771 + 256];
        float acc = 0.f;
        for (int d = 0; d < 256; d += 4) {
            float4 w = *reinterpret_cast<const float4*>(&wrow[d]);
            acc += w.x * out_proj_w[(d + 0) * 256 + e];
            acc += w.y * out_proj_w[(d + 1) * 256 + e];
            acc += w.z * out_proj_w[(d + 2) * 256 + e];
            acc += w.w * out_proj_w[(d + 3) * 256 + e];
        }
        WcatB[(256 + n) * 256 + e] = f2bf(acc);
    } else {
        // ---- qkv GEMM (raw fp32 inputs, inline cvt): 144 blocks, 64x64 ----
        const int q = blk - 1228;
        const int bm = q % 12, bn = q / 12;
        const int wv = threadIdx.x >> 6, lane = threadIdx.x & 63;
        const int l15 = lane & 15, quad = lane >> 4;
        const int row0 = bm * 64 + wv * 16;
        const int col0 = bn * 64;
        f32x4 acc[4] = {};
        for (int kc = 0; kc < 8; ++kc) {
            bf16x8 a = load8f_bf(&features[(row0 + l15) * 256 + kc * 32 + quad * 8]);
#pragma unroll
            for (int ct = 0; ct < 4; ++ct) {
                bf16x8 b = load8f_bf(&in_proj_w[(col0 + ct * 16 + l15) * 256 + kc * 32 + quad * 8]);
                acc[ct] = __builtin_amdgcn_mfma_f32_16x16x32_bf16(a, b, acc[ct], 0, 0, 0);
            }
        }
#pragma unroll
        for (int ct = 0; ct < 4; ++ct)
#pragma unroll
            for (int r = 0; r < 4; ++r) {
                int row = row0 + quad * 4 + r, col = col0 + ct * 16 + l15;
                float v = acc[ct][r] + in_proj_b[col];
                if (col < 512) qkvb[row * 768 + col] = f2bf(v);
                else           Vt[(col - 512) * 768 + row] = f2bf(v);
            }
    }
}

// ---------------- fused [att | AB] GEMM ------------------------------------
__global__ __launch_bounds__(256) void gemm_attab(
    const unsigned short* __restrict__ A, const unsigned short* __restrict__ W,
    const float* __restrict__ bias, float* __restrict__ att,
    float* __restrict__ AB)
{
    const int wv = threadIdx.x >> 6, lane = threadIdx.x & 63;
    const int l15 = lane & 15, quad = lane >> 4;
    const int row0 = blockIdx.x * 64 + wv * 16;
    const int col0 = blockIdx.y * 64;
    f32x4 acc[4] = {};
    for (int kc = 0; kc < 8; ++kc) {
        bf16x8 a = *reinterpret_cast<const bf16x8*>(&A[(row0 + l15) * 256 + kc * 32 + quad * 8]);
#pragma unroll
        for (int ct = 0; ct < 4; ++ct) {
            bf16x8 b = *reinterpret_cast<const bf16x8*>(&W[(col0 + ct * 16 + l15) * 256 + kc * 32 + quad * 8]);
            acc[ct] = __builtin_amdgcn_mfma_f32_16x16x32_bf16(a, b, acc[ct], 0, 0, 0);
        }
    }
#pragma unroll
    for (int ct = 0; ct < 4; ++ct)
#pragma unroll
        for (int r = 0; r < 4; ++r) {
            int row = row0 + quad * 4 + r, col = col0 + ct * 16 + l15;
            float v = acc[ct][r] + bias[col];
            if (col < 256) att[row * 256 + col] = v;
            else           AB[row * 512 + (col - 256)] = v;
        }
}

// ---------------- fused MFMA attention: 32-row q-tiles, 1-pass softmax -----
#define SP 776

__global__ __launch_bounds__(256) void attn_mfma(
    const unsigned short* __restrict__ qkvb, const unsigned short* __restrict__ Vt,
    unsigned short* __restrict__ Obf)
{
    __shared__ __align__(16) unsigned short smS[32 * SP];   // 49.7 KB
    __shared__ float s_inv[32];
    const int h = blockIdx.x, q0 = blockIdx.y * 32, hb = h * 32;
    const int tid = threadIdx.x, wave = tid >> 6, lane = tid & 63;
    const int l15 = lane & 15, quad = lane >> 4;

    bf16x8 af[2];
#pragma unroll
    for (int mt = 0; mt < 2; ++mt)
        af[mt] = *reinterpret_cast<const bf16x8*>(&qkvb[(q0 + mt * 16 + l15) * 768 + hb + quad * 8]);
#pragma unroll
    for (int ct = 0; ct < 12; ++ct) {
        int n0 = wave * 192 + ct * 16;
        bf16x8 b = *reinterpret_cast<const bf16x8*>(&qkvb[(n0 + l15) * 768 + 256 + hb + quad * 8]);
#pragma unroll
        for (int mt = 0; mt < 2; ++mt) {
            f32x4 c = {};
            c = __builtin_amdgcn_mfma_f32_16x16x32_bf16(af[mt], b, c, 0, 0, 0);
#pragma unroll
            for (int r = 0; r < 4; ++r)
                smS[(mt * 16 + quad * 4 + r) * SP + n0 + l15] =
                    f2bf(c[r] * 0.17677669529663689f);
        }
    }
    __syncthreads();

    {   // 1-pass softmax: exp (unnormalized, bounded scores) + row sum
        const int row = tid >> 3, part = tid & 7;
        unsigned short* rp = &smS[row * SP + part * 96];
        float ls = 0.f;
#pragma unroll
        for (int c8 = 0; c8 < 12; ++c8) {
            uint4 v = *reinterpret_cast<const uint4*>(&rp[c8 * 8]);
            const unsigned short* pe = reinterpret_cast<const unsigned short*>(&v);
            unsigned short o8[8];
#pragma unroll
            for (int e = 0; e < 8; ++e) {
                float ev = __expf(bf2f(pe[e]));
                ls += ev;
                o8[e] = f2bf(ev);
            }
            *reinterpret_cast<uint4*>(&rp[c8 * 8]) = *reinterpret_cast<const uint4*>(o8);
        }
        ls += __shfl_xor(ls, 1, 64);
        ls += __shfl_xor(ls, 2, 64);
        ls += __shfl_xor(ls, 4, 64);
        if (part == 0) s_inv[row] = 1.0f / ls;
    }
    __syncthreads();

    const int row0 = (wave >> 1) * 16, cg = wave & 1;
    f32x4 accp = {};
    for (int kc = 0; kc < 24; ++kc) {
        bf16x8 a = *reinterpret_cast<const bf16x8*>(&smS[(row0 + l15) * SP + kc * 32 + quad * 8]);
        bf16x8 b = *reinterpret_cast<const bf16x8*>(&Vt[(hb + cg * 16 + l15) * 768 + kc * 32 + quad * 8]);
        accp = __builtin_amdgcn_mfma_f32_16x16x32_bf16(a, b, accp, 0, 0, 0);
    }
#pragma unroll
    for (int r = 0; r < 4; ++r) {
        int rloc = row0 + quad * 4 + r;
        Obf[(q0 + rloc) * 256 + hb + cg * 16 + l15] = f2bf(accp[r] * s_inv[rloc]);
    }
}

// ---------------- fused pair MLP (MX fp8), 512 thr, 1 i x 64 j -------------
#define S1 304   // scaledA/h1 row stride: 288 data + 16 pad
#define S2 144   // h2 row stride: 128 data + 16 pad
#define S3 72    // h3 row stride: 64 data + 8 pad

__global__ __launch_bounds__(512, 2) void pair_mlp(
    const float* __restrict__ att, const float* __restrict__ AB,
    const unsigned char* __restrict__ w1c_mx, const unsigned char* __restrict__ w1t_f8,
    const unsigned char* __restrict__ w2g_mx, const unsigned char* __restrict__ w3_mx,
    const unsigned char* __restrict__ w4_f8,
    const float* __restrict__ boxes,
    const float* __restrict__ c1, const float* __restrict__ c2,
    const float* __restrict__ b3, const float* __restrict__ b4,
    const float* __restrict__ w5, const float* __restrict__ b5,
    float* __restrict__ out)
{
    __shared__ __align__(16) unsigned char smH[64 * S1];    // scaledA -> h1
    __shared__ __align__(16) unsigned char smH2[64 * S2];   // h2
    __shared__ __align__(16) unsigned char smH3[64 * S3];   // h3
    __shared__ float s_psum[64][8], s_pssq[64][8];
    __shared__ float s_mu[64], s_rs[64];
    __shared__ float s_l5[64][2];

    const int i    = blockIdx.x;
    const int j0   = blockIdx.y * 64;
    const int tid  = threadIdx.x;
    const int wave = tid >> 6;              // 0..7
    const int lane = tid & 63;
    const int l15  = lane & 15;
    const int quad = lane >> 4;

    // ---- stage scaledA fp8 from f32 att ----
    {
        const int g = tid & 63;
        float4 fi4 = *reinterpret_cast<const float4*>(&att[i * 256 + g * 4]);
#pragma unroll 4
        for (int it = 0; it < 8; ++it) {
            int r = (tid >> 6) + it * 8;
            float4 aj = *reinterpret_cast<const float4*>(&att[(j0 + r) * 256 + g * 4]);
            *reinterpret_cast<int*>(&smH[r * S1 + g * 4]) =
                pk4_fp8(aj.x * fi4.x, aj.y * fi4.y, aj.z * fi4.z, aj.w * fi4.w);
        }
    }
    if (tid < 64) {   // spatial tail cols 256..287
        int j = j0 + tid;
        float xd = fabsf(boxes[i * 4 + 0] - boxes[j * 4 + 0]);
        float yd = boxes[i * 4 + 1] - boxes[j * 4 + 1];
        *reinterpret_cast<int*>(&smH[tid * S1 + 256]) = pk4_fp8(xd, fabsf(yd), yd, 0.f);
        *reinterpret_cast<int*>(&smH[tid * S1 + 260]) = 0;
        *reinterpret_cast<long long*>(&smH[tid * S1 + 264]) = 0;
        *reinterpret_cast<long long*>(&smH[tid * S1 + 272]) = 0;
        *reinterpret_cast<long long*>(&smH[tid * S1 + 280]) = 0;
    }
    __syncthreads();                                          // B0

    // ======== GEMM1: wave owns o-slice 32 (2 mt tiles) ========
    f32x4 acc1[2][4] = {};   // [mt][nt]
#pragma unroll
    for (int ks = 0; ks < 2; ++ks) {
        i32x8 a0 = *reinterpret_cast<const i32x8*>(&w1c_mx[((ks * 16 + wave * 2 + 0) * 64 + lane) * 32]);
        i32x8 a1 = *reinterpret_cast<const i32x8*>(&w1c_mx[((ks * 16 + wave * 2 + 1) * 64 + lane) * 32]);
#pragma unroll
        for (int nt = 0; nt < 4; ++nt) {
            i32x8 b = ld32_lds(&smH[(nt * 16 + l15) * S1 + ks * 128 + quad * 32]);
            acc1[0][nt] = MFMA_MX(a0, b, acc1[0][nt]);
            acc1[1][nt] = MFMA_MX(a1, b, acc1[1][nt]);
        }
    }
    {   // spatial tail k = 256..287
        long long a0 = *reinterpret_cast<const long long*>(&w1t_f8[((wave * 2 + 0) * 64 + lane) * 8]);
        long long a1 = *reinterpret_cast<const long long*>(&w1t_f8[((wave * 2 + 1) * 64 + lane) * 8]);
#pragma unroll
        for (int nt = 0; nt < 4; ++nt) {
            long long b = *reinterpret_cast<const long long*>(&smH[(nt * 16 + l15) * S1 + 256 + quad * 8]);
            acc1[0][nt] = __builtin_amdgcn_mfma_f32_16x16x32_fp8_fp8(a0, b, acc1[0][nt], 0, 0, 0);
            acc1[1][nt] = __builtin_amdgcn_mfma_f32_16x16x32_fp8_fp8(a1, b, acc1[1][nt], 0, 0, 0);
        }
    }

    // ---- epilogue1: + A_i[o] + B_j[o], relu, stats ----
    const int o0 = wave * 32;
    float vsum[4] = {}, vssq[4] = {};
#pragma unroll
    for (int mt = 0; mt < 2; ++mt) {
        int o = o0 + mt * 16 + quad * 4;
        float4 Ai = *reinterpret_cast<const float4*>(&AB[i * 512 + o]);
        float AiA[4] = {Ai.x, Ai.y, Ai.z, Ai.w};
#pragma unroll
        for (int nt = 0; nt < 4; ++nt) {
            int j = nt * 16 + l15;
            float4 Bj = *reinterpret_cast<const float4*>(&AB[(j0 + j) * 512 + 256 + o]);
            float BjA[4] = {Bj.x, Bj.y, Bj.z, Bj.w};
#pragma unroll
            for (int r = 0; r < 4; ++r) {
                float v = fmaxf(acc1[mt][nt][r] + AiA[r] + BjA[r], 0.f);
                acc1[mt][nt][r] = v;
                vsum[nt] += v; vssq[nt] += v * v;
            }
        }
    }
#pragma unroll
    for (int nt = 0; nt < 4; ++nt) {
        vsum[nt] += __shfl_xor(vsum[nt], 16, 64);
        vsum[nt] += __shfl_xor(vsum[nt], 32, 64);
        vssq[nt] += __shfl_xor(vssq[nt], 16, 64);
        vssq[nt] += __shfl_xor(vssq[nt], 32, 64);
    }
    if (quad == 0)
#pragma unroll
        for (int nt = 0; nt < 4; ++nt) {
            s_psum[nt * 16 + l15][wave] = vsum[nt];
            s_pssq[nt * 16 + l15][wave] = vssq[nt];
        }
    __syncthreads();                                          // B1: GEMM1 reads done
    // h1 fp8 write into smH (overwrites scaledA; WAR cleared by B1)
#pragma unroll
    for (int mt = 0; mt < 2; ++mt) {
        int o = o0 + mt * 16 + quad * 4;
#pragma unroll
        for (int nt = 0; nt < 4; ++nt) {
            int j = nt * 16 + l15;
            *reinterpret_cast<int*>(&smH[j * S1 + o]) =
                pk4_fp8(acc1[mt][nt][0], acc1[mt][nt][1], acc1[mt][nt][2], acc1[mt][nt][3]);
        }
    }
    if (wave == 0) {   // finalize LN stats
        int j = lane;
        float sm = 0.f, sq = 0.f;
#pragma unroll
        for (int w = 0; w < 8; ++w) { sm += s_psum[j][w]; sq += s_pssq[j][w]; }
        sm *= (1.0f / 256.0f); sq *= (1.0f / 256.0f);
        s_mu[j] = sm;
        s_rs[j] = rsqrtf(sq - sm * sm + 1e-5f);
    }
    __syncthreads();                                          // B2: h1 + stats ready

    // ======== GEMM2 (MX, K=256): wave owns p-slice 16 ========
    f32x4 acc2[4] = {};
#pragma unroll
    for (int ks = 0; ks < 2; ++ks) {
        i32x8 a = *reinterpret_cast<const i32x8*>(&w2g_mx[((ks * 8 + wave) * 64 + lane) * 32]);
#pragma unroll
        for (int nt = 0; nt < 4; ++nt) {
            i32x8 b = ld32_lds(&smH[(nt * 16 + l15) * S1 + ks * 128 + quad * 32]);
            acc2[nt] = MFMA_MX(a, b, acc2[nt]);
        }
    }
    // epilogue2: LN-folded affine + relu -> h2 (separate region, no barrier)
    {
        int p = wave * 16 + quad * 4;
        float4 C1 = *reinterpret_cast<const float4*>(&c1[p]);
        float4 C2 = *reinterpret_cast<const float4*>(&c2[p]);
        float C1A[4] = {C1.x, C1.y, C1.z, C1.w};
        float C2A[4] = {C2.x, C2.y, C2.z, C2.w};
#pragma unroll
        for (int nt = 0; nt < 4; ++nt) {
            int j = nt * 16 + l15;
            float mu = s_mu[j], rs = s_rs[j];
            float vv[4];
#pragma unroll
            for (int r = 0; r < 4; ++r)
                vv[r] = fmaxf(rs * (acc2[nt][r] - mu * C2A[r]) + C1A[r], 0.f);
            *reinterpret_cast<int*>(&smH2[j * S2 + p]) = pk4_fp8(vv[0], vv[1], vv[2], vv[3]);
        }
    }
    __syncthreads();                                          // B3: h2 ready

    // ======== GEMM3 (MX, K=128): wave -> (q-tile, j-half) ========
    const int qt  = wave >> 1;      // 0..3 : q 16-tile
    const int jh2 = wave & 1;       // 0..1 : j 32-half
    f32x4 acc3[2] = {};
    {
        i32x8 a = *reinterpret_cast<const i32x8*>(&w3_mx[(qt * 64 + lane) * 32]);
#pragma unroll
        for (int ntl = 0; ntl < 2; ++ntl) {
            int j = (jh2 * 2 + ntl) * 16 + l15;
            i32x8 b = ld32_lds(&smH2[j * S2 + quad * 32]);
            acc3[ntl] = MFMA_MX(a, b, acc3[ntl]);
        }
    }
    {   // epilogue3 -> h3 (separate region, no pre-barrier)
        int q = qt * 16 + quad * 4;
        float4 B3 = *reinterpret_cast<const float4*>(&b3[q]);
        float B3A[4] = {B3.x, B3.y, B3.z, B3.w};
#pragma unroll
        for (int ntl = 0; ntl < 2; ++ntl) {
            int j = (jh2 * 2 + ntl) * 16 + l15;
            float vv[4];
#pragma unroll
            for (int r = 0; r < 4; ++r)
                vv[r] = fmaxf(acc3[ntl][r] + B3A[r], 0.f);
            *reinterpret_cast<int*>(&smH3[j * S3 + q]) = pk4_fp8(vv[0], vv[1], vv[2], vv[3]);
        }
    }
    __syncthreads();                                          // B4: h3 ready

    // ======== GEMM4 (16x16x32 fp8, K=64) + head: wave -> (o-tile, j-qtr) ====
    const int mt4 = wave & 1;       // o4 16-tile
    const int jq  = wave >> 1;      // 0..3 : j 16-quarter
    f32x4 acc4 = {};
#pragma unroll
    for (int kc = 0; kc < 2; ++kc) {
        long long a = *reinterpret_cast<const long long*>(&w4_f8[((kc * 2 + mt4) * 64 + lane) * 8]);
        int j = jq * 16 + l15;
        long long b = *reinterpret_cast<const long long*>(&smH3[j * S3 + kc * 32 + quad * 8]);
        acc4 = __builtin_amdgcn_mfma_f32_16x16x32_fp8_fp8(a, b, acc4, 0, 0, 0);
    }
    {
        int o4 = mt4 * 16 + quad * 4;
        float4 B4 = *reinterpret_cast<const float4*>(&b4[o4]);
        float4 W5 = *reinterpret_cast<const float4*>(&w5[o4]);
        float B4A[4] = {B4.x, B4.y, B4.z, B4.w};
        float W5A[4] = {W5.x, W5.y, W5.z, W5.w};
        float part = 0.f;
#pragma unroll
        for (int r = 0; r < 4; ++r)
            part += fmaxf(acc4[r] + B4A[r], 0.f) * W5A[r];
        part += __shfl_xor(part, 16, 64);
        part += __shfl_xor(part, 32, 64);
        if (quad == 0)
            s_l5[jq * 16 + l15][mt4] = part;
    }
    __syncthreads();                                          // B5
    if (tid < 64) {
        int j = j0 + tid;
        float v = s_l5[tid][0] + s_l5[tid][1] + b5[0];
        out[i * 768 + j] = (j == i) ? -1.0e9f : v;
    }
}

// ---------------------------------------------------------------------------
extern "C" void kernel_launch(void* const* d_in, const int* in_sizes, int n_in,
                              void* d_out, int out_size, void* d_ws, size_t ws_size,
                              hipStream_t stream)
{
    const float* features   = (const float*)d_in[0];
    const float* boxes      = (const float*)d_in[1];
    const float* in_proj_w  = (const float*)d_in[2];
    const float* in_proj_b  = (const float*)d_in[3];
    const float* out_proj_w = (const float*)d_in[4];
    const float* out_proj_b = (const float*)d_in[5];
    const float* w1  = (const float*)d_in[6];
    const float* b1  = (const float*)d_in[7];
    const float* ln_g = (const float*)d_in[8];
    const float* ln_b = (const float*)d_in[9];
    const float* w2  = (const float*)d_in[10];
    const float* b2  = (const float*)d_in[11];
    const float* w3  = (const float*)d_in[12];
    const float* b3  = (const float*)d_in[13];
    const float* w4  = (const float*)d_in[14];
    const float* b4  = (const float*)d_in[15];
    const float* w5  = (const float*)d_in[16];
    const float* b5  = (const float*)d_in[17];
    float* out = (float*)d_out;

    // ---- workspace layout ----
    char* p = (char*)d_ws;
    unsigned short* qkvb  = (unsigned short*)p; p += 768 * 768 * 2;
    unsigned short* Vt    = (unsigned short*)p; p += 256 * 768 * 2;
    unsigned short* Obf   = (unsigned short*)p; p += 768 * 256 * 2;
    unsigned short* WcatB = (unsigned short*)p; p += 196608 * 2;   // [outW;Wcomb]
    float* att = (float*)p; p += 768 * 256 * 4;
    float* AB  = (float*)p; p += 768 * 512 * 4;
    unsigned char* w1c_mx = (unsigned char*)p; p += 65536;
    unsigned char* w1t_f8 = (unsigned char*)p; p += 8192;
    unsigned char* w2g_mx = (unsigned char*)p; p += 32768;
    unsigned char* w3_mx  = (unsigned char*)p; p += 8192;
    unsigned char* w4_f8  = (unsigned char*)p; p += 2048;
    float* bias768 = (float*)p; p += 768 * 4;
    float* c1v     = (float*)p; p += 128 * 4;
    float* c2v     = (float*)p; p += 128 * 4;

    // 1) pack + Wcomb + qkv GEMM
    pack_all<<<dim3(1372), dim3(256), 0, stream>>>(features, in_proj_w,
        in_proj_b, out_proj_w, w1, w2, w3, w4, b1, ln_g, ln_b, b2, out_proj_b,
        qkvb, Vt, WcatB, w1c_mx, w1t_f8, w2g_mx, w3_mx, w4_f8,
        bias768, c1v, c2v);
    // 2) attention
    attn_mfma<<<dim3(8, 24), dim3(256), 0, stream>>>(qkvb, Vt, Obf);
    // 3) [att | AB] = O @ WcatB^T + bias768
    gemm_attab<<<dim3(12, 12), dim3(256), 0, stream>>>(Obf, WcatB, bias768,
        att, AB);
    // 4) pair MLP
    pair_mlp<<<dim3(768, 12), dim3(512), 0, stream>>>(att, AB,
        w1c_mx, w1t_f8, w2g_mx, w3_mx, w4_f8, boxes, c1v, c2v,
        b3, b4, w5, b5, out);
}

// Round 12
// 283.338 us; speedup vs baseline: 1.1145x; 1.0482x over previous
//
#include <hip/hip_runtime.h>

// ---------------------------------------------------------------------------
// ImprovedLinkingPredictor round 12.
// r11 + XOR-swizzled LDS in pair_mlp:
//  - scaledA: stride 384 (bank-neutral rows), 16B chunk swizzle c^=(j&15);
//    spatial tail staggered by (j&3)*24. MX 32B reads become conflict-free.
//  - h1 in its own region (stride 256, same swizzle) -> no WAR wait.
//  - h2: stride 192, chunk swizzle c^=(j&7).
// Front-end identical to r11.
// ---------------------------------------------------------------------------

typedef __attribute__((ext_vector_type(8))) __bf16 bf16x8;    // bf16 MFMA frag
typedef __attribute__((ext_vector_type(4))) float f32x4;      // 16x16 C/D
typedef __attribute__((ext_vector_type(8))) int i32x8;        // 32B fp8 frag

__device__ __forceinline__ float bf2f(unsigned short u) {
    return __uint_as_float(((unsigned int)u) << 16);
}
__device__ __forceinline__ unsigned short f2bf(float f) {
    union { __bf16 b; unsigned short u; } cv;
    cv.b = (__bf16)f;
    return cv.u;
}
__device__ __forceinline__ unsigned pk2(float lo, float hi) {
    return (unsigned)f2bf(lo) | ((unsigned)f2bf(hi) << 16);
}
__device__ __forceinline__ int pk4_fp8(float a, float b, float c, float d) {
    int w = __builtin_amdgcn_cvt_pk_fp8_f32(a, b, 0, false);
    w = __builtin_amdgcn_cvt_pk_fp8_f32(c, d, w, true);
    return w;
}
__device__ __forceinline__ unsigned char f2fp8(float v) {
    return (unsigned char)(__builtin_amdgcn_cvt_pk_fp8_f32(v, 0.f, 0, false) & 0xff);
}
__device__ __forceinline__ bf16x8 load8f_bf(const float* p) {
    float4 a = *reinterpret_cast<const float4*>(p);
    float4 b = *reinterpret_cast<const float4*>(p + 4);
    union { bf16x8 v; unsigned u[4]; } cv;
    cv.u[0] = pk2(a.x, a.y); cv.u[1] = pk2(a.z, a.w);
    cv.u[2] = pk2(b.x, b.y); cv.u[3] = pk2(b.z, b.w);
    return cv.v;
}
#define SC1 0x7F7F7F7F   // e8m0 scale = 1.0 in all bytes
#define MFMA_MX(a, b, c) __builtin_amdgcn_mfma_scale_f32_16x16x128_f8f6f4( \
        (a), (b), (c), 0, 0, 0, SC1, 0, SC1)

// ---------------- pack_all: packing + Wcomb + qkv GEMM ---------------------
__global__ __launch_bounds__(256) void pack_all(
    const float* __restrict__ features, const float* __restrict__ in_proj_w,
    const float* __restrict__ in_proj_b, const float* __restrict__ out_proj_w,
    const float* __restrict__ w1, const float* __restrict__ w2,
    const float* __restrict__ w3, const float* __restrict__ w4,
    const float* __restrict__ b1, const float* __restrict__ ln_g,
    const float* __restrict__ ln_b, const float* __restrict__ b2,
    const float* __restrict__ out_proj_b,
    unsigned short* __restrict__ qkvb, unsigned short* __restrict__ Vt,
    unsigned short* __restrict__ WcatB,
    unsigned char* __restrict__ w1c_mx, unsigned char* __restrict__ w1t_f8,
    unsigned char* __restrict__ w2g_mx, unsigned char* __restrict__ w3_mx,
    unsigned char* __restrict__ w4_f8,
    float* __restrict__ bias768, float* __restrict__ c1, float* __restrict__ c2)
{
    const int blk = blockIdx.x;
    if (blk < 716) {
        int t = blk * 256 + threadIdx.x;
        if (t < 65536) {                                // WcatB rows 0..255 = outW
            WcatB[t] = f2bf(out_proj_w[t]);
        } else if (t < 131072) {                        // w1c_mx: K=256 N=256, MX frag
            int u = t - 65536;
            int e = u & 31, lane = (u >> 5) & 63, f = u >> 11;
            int mt = f & 15, ks = f >> 4;
            int o = mt * 16 + (lane & 15);
            int k = ks * 128 + ((lane >> 4) & 3) * 32 + e;
            w1c_mx[u] = f2fp8(w1[o * 771 + 512 + k]);
        } else if (t < 139264) {                        // w1t_f8: spatial tail
            int u = t - 131072;
            int e = u & 7, lane = (u >> 3) & 63, f = u >> 9;
            int o = f * 16 + (lane & 15);
            int k = ((lane >> 4) & 3) * 8 + e;
            float v = (k < 3) ? w1[o * 771 + 768 + k] : 0.f;
            w1t_f8[u] = f2fp8(v);
        } else if (t < 172032) {                        // w2g_mx = w2*ln_g
            int u = t - 139264;
            int e = u & 31, lane = (u >> 5) & 63, f = u >> 11;
            int mt = f & 7, ks = f >> 3;
            int p = mt * 16 + (lane & 15);
            int k = ks * 128 + ((lane >> 4) & 3) * 32 + e;
            w2g_mx[u] = f2fp8(w2[p * 256 + k] * ln_g[k]);
        } else if (t < 180224) {                        // w3_mx: K=128 N=64
            int u = t - 172032;
            int e = u & 31, lane = (u >> 5) & 63, f = u >> 11;
            int o = f * 16 + (lane & 15);
            int k = ((lane >> 4) & 3) * 32 + e;
            w3_mx[u] = f2fp8(w3[o * 128 + k]);
        } else if (t < 182272) {                        // w4_f8 K=64 N=32 (16x16x32)
            int u = t - 180224;
            int e = u & 7, lane = (u >> 3) & 63, f = u >> 9;
            int l15 = lane & 15, quad = lane >> 4;
            int ct = f & 1, kc = f >> 1;
            int o = ct * 16 + l15, k = kc * 32 + quad * 8 + e;
            w4_f8[u] = f2fp8(w4[o * 64 + k]);
        } else if (t < 183040) {                        // bias768
            int n = t - 182272;
            if (n < 256) bias768[n] = out_proj_b[n];
            else {
                int m = n - 256;
                float s = 0.f;
                for (int d = 0; d < 256; d += 4) {
                    float4 ob = *reinterpret_cast<const float4*>(&out_proj_b[d]);
                    const float* wr = (m < 256) ? &w1[m * 771 + d]
                                                : &w1[(m - 256) * 771 + 256 + d];
                    float4 w = *reinterpret_cast<const float4*>(wr);
                    s += ob.x * w.x + ob.y * w.y + ob.z * w.z + ob.w * w.w;
                }
                bias768[n] = s + ((m < 256) ? b1[m] : 0.f);
            }
        } else if (t < 183168) {                        // c1/c2 LN-fold constants
            int p = t - 183040;
            float s2 = 0.f, s1 = 0.f;
            for (int k = 0; k < 256; k += 4) {
                float4 w = *reinterpret_cast<const float4*>(&w2[p * 256 + k]);
                float4 g = *reinterpret_cast<const float4*>(&ln_g[k]);
                float4 lb = *reinterpret_cast<const float4*>(&ln_b[k]);
                s2 += g.x * w.x + g.y * w.y + g.z * w.z + g.w * w.w;
                s1 += lb.x * w.x + lb.y * w.y + lb.z * w.z + lb.w * w.w;
            }
            c2[p] = s2;
            c1[p] = s1 + b2[p];
        }
    } else if (blk < 1228) {
        // ---- Wcomb[n][e] = sum_d wAB[n][d] * outW[d][e] -> WcatB rows 256+n
        const int n = blk - 716, e = threadIdx.x;
        const float* wrow = (n < 256) ? &w1[n * 771] : &w1[(n - 256) * 771 + 256];
        float acc = 0.f;
        for (int d = 0; d < 256; d += 4) {
            float4 w = *reinterpret_cast<const float4*>(&wrow[d]);
            acc += w.x * out_proj_w[(d + 0) * 256 + e];
            acc += w.y * out_proj_w[(d + 1) * 256 + e];
            acc += w.z * out_proj_w[(d + 2) * 256 + e];
            acc += w.w * out_proj_w[(d + 3) * 256 + e];
        }
        WcatB[(256 + n) * 256 + e] = f2bf(acc);
    } else {
        // ---- qkv GEMM (raw fp32 inputs, inline cvt): 144 blocks, 64x64 ----
        const int q = blk - 1228;
        const int bm = q % 12, bn = q / 12;
        const int wv = threadIdx.x >> 6, lane = threadIdx.x & 63;
        const int l15 = lane & 15, quad = lane >> 4;
        const int row0 = bm * 64 + wv * 16;
        const int col0 = bn * 64;
        f32x4 acc[4] = {};
        for (int kc = 0; kc < 8; ++kc) {
            bf16x8 a = load8f_bf(&features[(row0 + l15) * 256 + kc * 32 + quad * 8]);
#pragma unroll
            for (int ct = 0; ct < 4; ++ct) {
                bf16x8 b = load8f_bf(&in_proj_w[(col0 + ct * 16 + l15) * 256 + kc * 32 + quad * 8]);
                acc[ct] = __builtin_amdgcn_mfma_f32_16x16x32_bf16(a, b, acc[ct], 0, 0, 0);
            }
        }
#pragma unroll
        for (int ct = 0; ct < 4; ++ct)
#pragma unroll
            for (int r = 0; r < 4; ++r) {
                int row = row0 + quad * 4 + r, col = col0 + ct * 16 + l15;
                float v = acc[ct][r] + in_proj_b[col];
                if (col < 512) qkvb[row * 768 + col] = f2bf(v);
                else           Vt[(col - 512) * 768 + row] = f2bf(v);
            }
    }
}

// ---------------- fused [att | AB] GEMM ------------------------------------
__global__ __launch_bounds__(256) void gemm_attab(
    const unsigned short* __restrict__ A, const unsigned short* __restrict__ W,
    const float* __restrict__ bias, float* __restrict__ att,
    float* __restrict__ AB)
{
    const int wv = threadIdx.x >> 6, lane = threadIdx.x & 63;
    const int l15 = lane & 15, quad = lane >> 4;
    const int row0 = blockIdx.x * 64 + wv * 16;
    const int col0 = blockIdx.y * 64;
    f32x4 acc[4] = {};
    for (int kc = 0; kc < 8; ++kc) {
        bf16x8 a = *reinterpret_cast<const bf16x8*>(&A[(row0 + l15) * 256 + kc * 32 + quad * 8]);
#pragma unroll
        for (int ct = 0; ct < 4; ++ct) {
            bf16x8 b = *reinterpret_cast<const bf16x8*>(&W[(col0 + ct * 16 + l15) * 256 + kc * 32 + quad * 8]);
            acc[ct] = __builtin_amdgcn_mfma_f32_16x16x32_bf16(a, b, acc[ct], 0, 0, 0);
        }
    }
#pragma unroll
    for (int ct = 0; ct < 4; ++ct)
#pragma unroll
        for (int r = 0; r < 4; ++r) {
            int row = row0 + quad * 4 + r, col = col0 + ct * 16 + l15;
            float v = acc[ct][r] + bias[col];
            if (col < 256) att[row * 256 + col] = v;
            else           AB[row * 512 + (col - 256)] = v;
        }
}

// ---------------- fused MFMA attention: 32-row q-tiles, 1-pass softmax -----
#define SP 776

__global__ __launch_bounds__(256) void attn_mfma(
    const unsigned short* __restrict__ qkvb, const unsigned short* __restrict__ Vt,
    unsigned short* __restrict__ Obf)
{
    __shared__ __align__(16) unsigned short smS[32 * SP];   // 49.7 KB
    __shared__ float s_inv[32];
    const int h = blockIdx.x, q0 = blockIdx.y * 32, hb = h * 32;
    const int tid = threadIdx.x, wave = tid >> 6, lane = tid & 63;
    const int l15 = lane & 15, quad = lane >> 4;

    bf16x8 af[2];
#pragma unroll
    for (int mt = 0; mt < 2; ++mt)
        af[mt] = *reinterpret_cast<const bf16x8*>(&qkvb[(q0 + mt * 16 + l15) * 768 + hb + quad * 8]);
#pragma unroll
    for (int ct = 0; ct < 12; ++ct) {
        int n0 = wave * 192 + ct * 16;
        bf16x8 b = *reinterpret_cast<const bf16x8*>(&qkvb[(n0 + l15) * 768 + 256 + hb + quad * 8]);
#pragma unroll
        for (int mt = 0; mt < 2; ++mt) {
            f32x4 c = {};
            c = __builtin_amdgcn_mfma_f32_16x16x32_bf16(af[mt], b, c, 0, 0, 0);
#pragma unroll
            for (int r = 0; r < 4; ++r)
                smS[(mt * 16 + quad * 4 + r) * SP + n0 + l15] =
                    f2bf(c[r] * 0.17677669529663689f);
        }
    }
    __syncthreads();

    {   // 1-pass softmax: exp (unnormalized, bounded scores) + row sum
        const int row = tid >> 3, part = tid & 7;
        unsigned short* rp = &smS[row * SP + part * 96];
        float ls = 0.f;
#pragma unroll
        for (int c8 = 0; c8 < 12; ++c8) {
            uint4 v = *reinterpret_cast<const uint4*>(&rp[c8 * 8]);
            const unsigned short* pe = reinterpret_cast<const unsigned short*>(&v);
            unsigned short o8[8];
#pragma unroll
            for (int e = 0; e < 8; ++e) {
                float ev = __expf(bf2f(pe[e]));
                ls += ev;
                o8[e] = f2bf(ev);
            }
            *reinterpret_cast<uint4*>(&rp[c8 * 8]) = *reinterpret_cast<const uint4*>(o8);
        }
        ls += __shfl_xor(ls, 1, 64);
        ls += __shfl_xor(ls, 2, 64);
        ls += __shfl_xor(ls, 4, 64);
        if (part == 0) s_inv[row] = 1.0f / ls;
    }
    __syncthreads();

    const int row0 = (wave >> 1) * 16, cg = wave & 1;
    f32x4 accp = {};
    for (int kc = 0; kc < 24; ++kc) {
        bf16x8 a = *reinterpret_cast<const bf16x8*>(&smS[(row0 + l15) * SP + kc * 32 + quad * 8]);
        bf16x8 b = *reinterpret_cast<const bf16x8*>(&Vt[(hb + cg * 16 + l15) * 768 + kc * 32 + quad * 8]);
        accp = __builtin_amdgcn_mfma_f32_16x16x32_bf16(a, b, accp, 0, 0, 0);
    }
#pragma unroll
    for (int r = 0; r < 4; ++r) {
        int rloc = row0 + quad * 4 + r;
        Obf[(q0 + rloc) * 256 + hb + cg * 16 + l15] = f2bf(accp[r] * s_inv[rloc]);
    }
}

// ---------------- fused pair MLP (MX fp8, swizzled LDS), 512 thr -----------
// smH  (scaledA): stride 384. k<256 in 16B chunks at c' = c ^ (j&15);
//                 tail (k 256..287) at byte 256 + (j&3)*24 + g*8.
// smH1 (h1): stride 256, chunks c' = c ^ (j&15).
// smH2 (h2): stride 192, chunks c' = c ^ (j&7).
// smH3 (h3): stride 72, plain.
__global__ __launch_bounds__(512, 2) void pair_mlp(
    const float* __restrict__ att, const float* __restrict__ AB,
    const unsigned char* __restrict__ w1c_mx, const unsigned char* __restrict__ w1t_f8,
    const unsigned char* __restrict__ w2g_mx, const unsigned char* __restrict__ w3_mx,
    const unsigned char* __restrict__ w4_f8,
    const float* __restrict__ boxes,
    const float* __restrict__ c1, const float* __restrict__ c2,
    const float* __restrict__ b3, const float* __restrict__ b4,
    const float* __restrict__ w5, const float* __restrict__ b5,
    float* __restrict__ out)
{
    __shared__ __align__(16) unsigned char smH[64 * 384];   // scaledA (24.6 KB)
    __shared__ __align__(16) unsigned char smH1[64 * 256];  // h1 (16 KB)
    __shared__ __align__(16) unsigned char smH2[64 * 192];  // h2 (12 KB)
    __shared__ __align__(16) unsigned char smH3[64 * 72];   // h3 (4.6 KB)
    __shared__ float s_psum[64][8], s_pssq[64][8];
    __shared__ float s_mu[64], s_rs[64];
    __shared__ float s_l5[64][2];

    const int i    = blockIdx.x;
    const int j0   = blockIdx.y * 64;
    const int tid  = threadIdx.x;
    const int wave = tid >> 6;              // 0..7
    const int lane = tid & 63;
    const int l15  = lane & 15;
    const int quad = lane >> 4;

    // ---- stage scaledA fp8 (swizzled) ----
    {
        const int g = tid & 63;             // dword index 0..63
        const int ch = g >> 2;              // 16B chunk 0..15
        float4 fi4 = *reinterpret_cast<const float4*>(&att[i * 256 + g * 4]);
#pragma unroll 4
        for (int it = 0; it < 8; ++it) {
            int r = (tid >> 6) + it * 8;
            float4 aj = *reinterpret_cast<const float4*>(&att[(j0 + r) * 256 + g * 4]);
            int cs = ch ^ (r & 15);
            *reinterpret_cast<int*>(&smH[r * 384 + cs * 16 + (g & 3) * 4]) =
                pk4_fp8(aj.x * fi4.x, aj.y * fi4.y, aj.z * fi4.z, aj.w * fi4.w);
        }
    }
    if (tid < 64) {   // spatial tail, staggered by (j&3)*24
        int j = j0 + tid;
        float xd = fabsf(boxes[i * 4 + 0] - boxes[j * 4 + 0]);
        float yd = boxes[i * 4 + 1] - boxes[j * 4 + 1];
        unsigned char* tb = &smH[tid * 384 + 256 + (tid & 3) * 24];
        *reinterpret_cast<int*>(tb)      = pk4_fp8(xd, fabsf(yd), yd, 0.f);
        *reinterpret_cast<int*>(tb + 4)  = 0;
        *reinterpret_cast<long long*>(tb + 8)  = 0;
        *reinterpret_cast<long long*>(tb + 16) = 0;
        *reinterpret_cast<long long*>(tb + 24) = 0;
    }
    __syncthreads();                                          // B0

    // ======== GEMM1: wave owns o-slice 32 ========
    f32x4 acc1[2][4] = {};   // [mt][nt]
#pragma unroll
    for (int ks = 0; ks < 2; ++ks) {
        i32x8 a0 = *reinterpret_cast<const i32x8*>(&w1c_mx[((ks * 16 + wave * 2 + 0) * 64 + lane) * 32]);
        i32x8 a1 = *reinterpret_cast<const i32x8*>(&w1c_mx[((ks * 16 + wave * 2 + 1) * 64 + lane) * 32]);
        const int cb = ks * 8 + quad * 2;
#pragma unroll
        for (int nt = 0; nt < 4; ++nt) {
            const unsigned char* rp = &smH[(nt * 16 + l15) * 384];
            union { i32x8 v; uint4 q[2]; } b;
            b.q[0] = *reinterpret_cast<const uint4*>(rp + ((cb    ) ^ l15) * 16);
            b.q[1] = *reinterpret_cast<const uint4*>(rp + ((cb + 1) ^ l15) * 16);
            acc1[0][nt] = MFMA_MX(a0, b.v, acc1[0][nt]);
            acc1[1][nt] = MFMA_MX(a1, b.v, acc1[1][nt]);
        }
    }
    {   // spatial tail k = 256..287
        long long a0 = *reinterpret_cast<const long long*>(&w1t_f8[((wave * 2 + 0) * 64 + lane) * 8]);
        long long a1 = *reinterpret_cast<const long long*>(&w1t_f8[((wave * 2 + 1) * 64 + lane) * 8]);
#pragma unroll
        for (int nt = 0; nt < 4; ++nt) {
            long long b = *reinterpret_cast<const long long*>(
                &smH[(nt * 16 + l15) * 384 + 256 + (l15 & 3) * 24 + quad * 8]);
            acc1[0][nt] = __builtin_amdgcn_mfma_f32_16x16x32_fp8_fp8(a0, b, acc1[0][nt], 0, 0, 0);
            acc1[1][nt] = __builtin_amdgcn_mfma_f32_16x16x32_fp8_fp8(a1, b, acc1[1][nt], 0, 0, 0);
        }
    }

    // ---- epilogue1: + A_i[o] + B_j[o], relu, stats ----
    const int o0 = wave * 32;
    float vsum[4] = {}, vssq[4] = {};
#pragma unroll
    for (int mt = 0; mt < 2; ++mt) {
        int o = o0 + mt * 16 + quad * 4;
        float4 Ai = *reinterpret_cast<const float4*>(&AB[i * 512 + o]);
        float AiA[4] = {Ai.x, Ai.y, Ai.z, Ai.w};
#pragma unroll
        for (int nt = 0; nt < 4; ++nt) {
            int j = nt * 16 + l15;
            float4 Bj = *reinterpret_cast<const float4*>(&AB[(j0 + j) * 512 + 256 + o]);
            float BjA[4] = {Bj.x, Bj.y, Bj.z, Bj.w};
#pragma unroll
            for (int r = 0; r < 4; ++r) {
                float v = fmaxf(acc1[mt][nt][r] + AiA[r] + BjA[r], 0.f);
                acc1[mt][nt][r] = v;
                vsum[nt] += v; vssq[nt] += v * v;
            }
        }
    }
#pragma unroll
    for (int nt = 0; nt < 4; ++nt) {
        vsum[nt] += __shfl_xor(vsum[nt], 16, 64);
        vsum[nt] += __shfl_xor(vsum[nt], 32, 64);
        vssq[nt] += __shfl_xor(vssq[nt], 16, 64);
        vssq[nt] += __shfl_xor(vssq[nt], 32, 64);
    }
    if (quad == 0)
#pragma unroll
        for (int nt = 0; nt < 4; ++nt) {
            s_psum[nt * 16 + l15][wave] = vsum[nt];
            s_pssq[nt * 16 + l15][wave] = vssq[nt];
        }
    // h1 fp8 write -> smH1 (separate region: no WAR wait needed)
#pragma unroll
    for (int mt = 0; mt < 2; ++mt) {
        const int ch = wave * 2 + mt;       // o chunk 0..15
#pragma unroll
        for (int nt = 0; nt < 4; ++nt) {
            int j = nt * 16 + l15;
            *reinterpret_cast<int*>(&smH1[j * 256 + (ch ^ l15) * 16 + quad * 4]) =
                pk4_fp8(acc1[mt][nt][0], acc1[mt][nt][1], acc1[mt][nt][2], acc1[mt][nt][3]);
        }
    }
    __syncthreads();                                          // B1: h1 + psum ready
    if (wave == 0) {   // finalize LN stats (before wave0's GEMM2)
        int j = lane;
        float sm = 0.f, sq = 0.f;
#pragma unroll
        for (int w = 0; w < 8; ++w) { sm += s_psum[j][w]; sq += s_pssq[j][w]; }
        sm *= (1.0f / 256.0f); sq *= (1.0f / 256.0f);
        s_mu[j] = sm;
        s_rs[j] = rsqrtf(sq - sm * sm + 1e-5f);
    }

    // ======== GEMM2 (MX, K=256): wave owns p-slice 16 ========
    f32x4 acc2[4] = {};
#pragma unroll
    for (int ks = 0; ks < 2; ++ks) {
        i32x8 a = *reinterpret_cast<const i32x8*>(&w2g_mx[((ks * 8 + wave) * 64 + lane) * 32]);
        const int cb = ks * 8 + quad * 2;
#pragma unroll
        for (int nt = 0; nt < 4; ++nt) {
            const unsigned char* rp = &smH1[(nt * 16 + l15) * 256];
            union { i32x8 v; uint4 q[2]; } b;
            b.q[0] = *reinterpret_cast<const uint4*>(rp + ((cb    ) ^ l15) * 16);
            b.q[1] = *reinterpret_cast<const uint4*>(rp + ((cb + 1) ^ l15) * 16);
            acc2[nt] = MFMA_MX(a, b.v, acc2[nt]);
        }
    }
    __syncthreads();                                          // B2: stats ready
    // epilogue2: LN-folded affine + relu -> h2 (swizzled)
    {
        int p = wave * 16 + quad * 4;
        float4 C1 = *reinterpret_cast<const float4*>(&c1[p]);
        float4 C2 = *reinterpret_cast<const float4*>(&c2[p]);
        float C1A[4] = {C1.x, C1.y, C1.z, C1.w};
        float C2A[4] = {C2.x, C2.y, C2.z, C2.w};
#pragma unroll
        for (int nt = 0; nt < 4; ++nt) {
            int j = nt * 16 + l15;
            float mu = s_mu[j], rs = s_rs[j];
            float vv[4];
#pragma unroll
            for (int r = 0; r < 4; ++r)
                vv[r] = fmaxf(rs * (acc2[nt][r] - mu * C2A[r]) + C1A[r], 0.f);
            *reinterpret_cast<int*>(&smH2[j * 192 + (wave ^ (l15 & 7)) * 16 + quad * 4]) =
                pk4_fp8(vv[0], vv[1], vv[2], vv[3]);
        }
    }
    __syncthreads();                                          // B3: h2 ready

    // ======== GEMM3 (MX, K=128): wave -> (q-tile, j-half) ========
    const int qt  = wave >> 1;      // 0..3 : q 16-tile
    const int jh2 = wave & 1;       // 0..1 : j 32-half
    f32x4 acc3[2] = {};
    {
        i32x8 a = *reinterpret_cast<const i32x8*>(&w3_mx[(qt * 64 + lane) * 32]);
        const int cb = quad * 2;
#pragma unroll
        for (int ntl = 0; ntl < 2; ++ntl) {
            int j = (jh2 * 2 + ntl) * 16 + l15;
            const unsigned char* rp = &smH2[j * 192];
            union { i32x8 v; uint4 q[2]; } b;
            b.q[0] = *reinterpret_cast<const uint4*>(rp + ((cb    ) ^ (l15 & 7)) * 16);
            b.q[1] = *reinterpret_cast<const uint4*>(rp + ((cb + 1) ^ (l15 & 7)) * 16);
            acc3[ntl] = MFMA_MX(a, b.v, acc3[ntl]);
        }
    }
    {   // epilogue3 -> h3 (plain, separate region)
        int q = qt * 16 + quad * 4;
        float4 B3 = *reinterpret_cast<const float4*>(&b3[q]);
        float B3A[4] = {B3.x, B3.y, B3.z, B3.w};
#pragma unroll
        for (int ntl = 0; ntl < 2; ++ntl) {
            int j = (jh2 * 2 + ntl) * 16 + l15;
            float vv[4];
#pragma unroll
            for (int r = 0; r < 4; ++r)
                vv[r] = fmaxf(acc3[ntl][r] + B3A[r], 0.f);
            *reinterpret_cast<int*>(&smH3[j * 72 + q]) = pk4_fp8(vv[0], vv[1], vv[2], vv[3]);
        }
    }
    __syncthreads();                                          // B4: h3 ready

    // ======== GEMM4 (16x16x32 fp8, K=64) + head ========
    const int mt4 = wave & 1;       // o4 16-tile
    const int jq  = wave >> 1;      // 0..3 : j 16-quarter
    f32x4 acc4 = {};
#pragma unroll
    for (int kc = 0; kc < 2; ++kc) {
        long long a = *reinterpret_cast<const long long*>(&w4_f8[((kc * 2 + mt4) * 64 + lane) * 8]);
        int j = jq * 16 + l15;
        long long b = *reinterpret_cast<const long long*>(&smH3[j * 72 + kc * 32 + quad * 8]);
        acc4 = __builtin_amdgcn_mfma_f32_16x16x32_fp8_fp8(a, b, acc4, 0, 0, 0);
    }
    {
        int o4 = mt4 * 16 + quad * 4;
        float4 B4 = *reinterpret_cast<const float4*>(&b4[o4]);
        float4 W5 = *reinterpret_cast<const float4*>(&w5[o4]);
        float B4A[4] = {B4.x, B4.y, B4.z, B4.w};
        float W5A[4] = {W5.x, W5.y, W5.z, W5.w};
        float part = 0.f;
#pragma unroll
        for (int r = 0; r < 4; ++r)
            part += fmaxf(acc4[r] + B4A[r], 0.f) * W5A[r];
        part += __shfl_xor(part, 16, 64);
        part += __shfl_xor(part, 32, 64);
        if (quad == 0)
            s_l5[jq * 16 + l15][mt4] = part;
    }
    __syncthreads();                                          // B5
    if (tid < 64) {
        int j = j0 + tid;
        float v = s_l5[tid][0] + s_l5[tid][1] + b5[0];
        out[i * 768 + j] = (j == i) ? -1.0e9f : v;
    }
}

// ---------------------------------------------------------------------------
extern "C" void kernel_launch(void* const* d_in, const int* in_sizes, int n_in,
                              void* d_out, int out_size, void* d_ws, size_t ws_size,
                              hipStream_t stream)
{
    const float* features   = (const float*)d_in[0];
    const float* boxes      = (const float*)d_in[1];
    const float* in_proj_w  = (const float*)d_in[2];
    const float* in_proj_b  = (const float*)d_in[3];
    const float* out_proj_w = (const float*)d_in[4];
    const float* out_proj_b = (const float*)d_in[5];
    const float* w1  = (const float*)d_in[6];
    const float* b1  = (const float*)d_in[7];
    const float* ln_g = (const float*)d_in[8];
    const float* ln_b = (const float*)d_in[9];
    const float* w2  = (const float*)d_in[10];
    const float* b2  = (const float*)d_in[11];
    const float* w3  = (const float*)d_in[12];
    const float* b3  = (const float*)d_in[13];
    const float* w4  = (const float*)d_in[14];
    const float* b4  = (const float*)d_in[15];
    const float* w5  = (const float*)d_in[16];
    const float* b5  = (const float*)d_in[17];
    float* out = (float*)d_out;

    // ---- workspace layout ----
    char* p = (char*)d_ws;
    unsigned short* qkvb  = (unsigned short*)p; p += 768 * 768 * 2;
    unsigned short* Vt    = (unsigned short*)p; p += 256 * 768 * 2;
    unsigned short* Obf   = (unsigned short*)p; p += 768 * 256 * 2;
    unsigned short* WcatB = (unsigned short*)p; p += 196608 * 2;   // [outW;Wcomb]
    float* att = (float*)p; p += 768 * 256 * 4;
    float* AB  = (float*)p; p += 768 * 512 * 4;
    unsigned char* w1c_mx = (unsigned char*)p; p += 65536;
    unsigned char* w1t_f8 = (unsigned char*)p; p += 8192;
    unsigned char* w2g_mx = (unsigned char*)p; p += 32768;
    unsigned char* w3_mx  = (unsigned char*)p; p += 8192;
    unsigned char* w4_f8  = (unsigned char*)p; p += 2048;
    float* bias768 = (float*)p; p += 768 * 4;
    float* c1v     = (float*)p; p += 128 * 4;
    float* c2v     = (float*)p; p += 128 * 4;

    // 1) pack + Wcomb + qkv GEMM
    pack_all<<<dim3(1372), dim3(256), 0, stream>>>(features, in_proj_w,
        in_proj_b, out_proj_w, w1, w2, w3, w4, b1, ln_g, ln_b, b2, out_proj_b,
        qkvb, Vt, WcatB, w1c_mx, w1t_f8, w2g_mx, w3_mx, w4_f8,
        bias768, c1v, c2v);
    // 2) attention
    attn_mfma<<<dim3(8, 24), dim3(256), 0, stream>>>(qkvb, Vt, Obf);
    // 3) [att | AB] = O @ WcatB^T + bias768
    gemm_attab<<<dim3(12, 12), dim3(256), 0, stream>>>(Obf, WcatB, bias768,
        att, AB);
    // 4) pair MLP
    pair_mlp<<<dim3(768, 12), dim3(512), 0, stream>>>(att, AB,
        w1c_mx, w1t_f8, w2g_mx, w3_mx, w4_f8, boxes, c1v, c2v,
        b3, b4, w5, b5, out);
}